// Round 5
// baseline (17.958 us; speedup 1.0000x reference)
//
#include <hip/hip_runtime.h>

// probs [N,T,K] f32, targets [N,L] int32
constexpr int N_ = 32;
constexpr int T_ = 256;
constexpr int K_ = 8000;
constexpr int L_ = 64;
constexpr int TCH = 16;                  // t's (waves) per block
constexpr int NBLK1 = N_ * (T_ / TCH);   // 512 blocks x 1024 threads

// Kernel 1: wave = one (n,t) row. Lane l gathers probs[n][t][targets[n][l]]
// -> all 64 requests land in one 32KB row (DRAM row-buffer hits + line
// merge for close targets). 16 waves/block = 16 t's of one n; LDS-combine
// to ws2[n][chunk][l] (chunk-partial column sums).
__global__ __launch_bounds__(1024) void ACE_gather(
    const float* __restrict__ probs,
    const int* __restrict__ targets,
    float* __restrict__ ws2) {            // [N][T/TCH][64]
    const int w = threadIdx.x >> 6;       // 0..15: t offset within chunk
    const int lane = threadIdx.x & 63;    // == l
    const int n = blockIdx.x >> 4;        // blockIdx = n*16 + chunk
    const int chunk = blockIdx.x & 15;
    const int t = chunk * TCH + w;

    const int k = targets[(n << 6) + lane];            // L2-hot after warmup
    const float v = probs[((size_t)(n * T_ + t)) * (size_t)K_ + (size_t)k];

    __shared__ float lds[TCH * 64];
    lds[(w << 6) + lane] = v;
    __syncthreads();

    if (w == 0) {
        // lane reads lds[j*64+lane]: bank = lane%32 -> 2-way across 64 lanes
        // (free, m136). 16 serial reads, deterministic order.
        float s = 0.0f;
        #pragma unroll
        for (int j = 0; j < TCH; ++j)
            s += lds[(j << 6) + lane];
        ws2[(((n << 4) + chunk) << 6) + lane] = s;
    }
}

// Kernel 2: single block finishes everything: per-column chunk-sum (16
// values), -log(mean + eps), then global mean. Data = 128KB, L3-hot.
__global__ __launch_bounds__(256) void ACE_finish(
    const float* __restrict__ ws2,
    float* __restrict__ out) {
    const int tid = threadIdx.x;          // 256 threads, 8 columns each
    float s = 0.0f;
    #pragma unroll
    for (int j = 0; j < 8; ++j) {
        const int c = tid + (j << 8);     // column id = n*64 + l
        const int n = c >> 6;
        const int l = c & 63;
        float cs = 0.0f;
        #pragma unroll
        for (int ch = 0; ch < 16; ++ch)
            cs += ws2[(((n << 4) + ch) << 6) + l];
        s += -logf(cs * (1.0f / (float)T_) + 1e-10f);
    }
    #pragma unroll
    for (int off = 32; off > 0; off >>= 1)
        s += __shfl_down(s, off, 64);
    __shared__ float wsum[4];
    if ((tid & 63) == 0) wsum[tid >> 6] = s;
    __syncthreads();
    if (tid == 0)
        out[0] = (wsum[0] + wsum[1] + wsum[2] + wsum[3])
                 * (1.0f / ((float)N_ * (float)T_));
}

extern "C" void kernel_launch(void* const* d_in, const int* in_sizes, int n_in,
                              void* d_out, int out_size, void* d_ws, size_t ws_size,
                              hipStream_t stream) {
    const float* probs = (const float*)d_in[0];
    const int* targets = (const int*)d_in[1];
    float* out = (float*)d_out;
    float* ws2 = (float*)d_ws;            // 32*16*64 floats = 128 KB

    ACE_gather<<<NBLK1, 1024, 0, stream>>>(probs, targets, ws2);
    ACE_finish<<<1, 256, 0, stream>>>(ws2, out);
}